// Round 20
// baseline (961.609 us; speedup 1.0000x reference)
//
#include <hip/hip_runtime.h>
#include <math.h>

#define NN 50000
#define NE 800000
#define F_IN 64
#define HID 128
#define HEADS 4
#define LAYERS 3

typedef __attribute__((ext_vector_type(8))) short bf16x8;
typedef __attribute__((ext_vector_type(8))) unsigned short ushort8;
typedef __attribute__((ext_vector_type(4))) float f32x4;
typedef __attribute__((ext_vector_type(4))) unsigned int u32x4;
typedef __attribute__((ext_vector_type(2))) unsigned int u32x2;

__device__ __forceinline__ float b2f(unsigned short u) {
  return __builtin_bit_cast(float, ((unsigned int)u) << 16);
}
__device__ __forceinline__ unsigned short f2bf(float f) {
  unsigned int u = __builtin_bit_cast(unsigned int, f);
  u = (u + 0x7FFFu + ((u >> 16) & 1u)) >> 16;
  return (unsigned short)u;
}
__device__ __forceinline__ float bitf(unsigned int u) {
  return __builtin_bit_cast(float, u);
}

__device__ __forceinline__ void gload16(const void* g, void* l) {
  __builtin_amdgcn_global_load_lds(
      (const __attribute__((address_space(1))) unsigned int*)g,
      (__attribute__((address_space(3))) unsigned int*)l, 16, 0, 0);
}

// ---------------- CSR build ----------------

__global__ void hist_kernel(const int* __restrict__ dst, int* __restrict__ counts, int E) {
  int e = blockIdx.x * blockDim.x + threadIdx.x;
  if (e < E) atomicAdd(&counts[dst[e]], 1);
}

__global__ void scan1_kernel(const int* __restrict__ counts, int* __restrict__ indptr,
                             int* __restrict__ bsum, int n) {
  __shared__ int buf[1024];
  int tid = threadIdx.x;
  int i = blockIdx.x * 1024 + tid;
  int v = (i < n) ? counts[i] : 0;
  buf[tid] = v;
  __syncthreads();
  for (int off = 1; off < 1024; off <<= 1) {
    int t = (tid >= off) ? buf[tid - off] : 0;
    __syncthreads();
    buf[tid] += t;
    __syncthreads();
  }
  if (i < n) indptr[i] = buf[tid] - v;
  if (tid == 1023) bsum[blockIdx.x] = buf[1023];
}

__global__ void scan2_kernel(int* __restrict__ bsum, int* __restrict__ boff,
                             int nb, int* __restrict__ indptr, int n) {
  if (threadIdx.x == 0 && blockIdx.x == 0) {
    int s = 0;
    for (int c = 0; c < nb; ++c) { boff[c] = s; s += bsum[c]; }
    indptr[n] = s;
  }
}

__global__ void scan3_kernel(int* __restrict__ indptr, const int* __restrict__ boff, int n) {
  int i = blockIdx.x * 1024 + threadIdx.x;
  if (i < n) indptr[i] += boff[blockIdx.x];
}

__global__ void scatter_kernel(const int* __restrict__ src, const int* __restrict__ dst,
                               const int* __restrict__ indptr, int* __restrict__ fill,
                               int* __restrict__ srcs, int E) {
  int e = blockIdx.x * blockDim.x + threadIdx.x;
  if (e < E) {
    int d = dst[e];
    int pos = atomicAdd(&fill[d], 1);
    srcs[indptr[d] + pos] = src[e];
  }
}

// ---------------- degree-sorted node permutation (counting sort, 64 bins) ----------------

__global__ void dhist_kernel(const int* __restrict__ indptr, int* __restrict__ dbins) {
  int i = blockIdx.x * 256 + threadIdx.x;
  if (i < NN) {
    int deg = indptr[i + 1] - indptr[i];
    if (deg > 63) deg = 63;
    atomicAdd(&dbins[deg], 1);
  }
}

__global__ void dscan_kernel(const int* __restrict__ dbins, int* __restrict__ doff) {
  if (threadIdx.x == 0 && blockIdx.x == 0) {
    int s = 0;
    for (int b = 0; b < 64; ++b) { doff[b] = s; s += dbins[b]; }
  }
}

__global__ void dscatter_kernel(const int* __restrict__ indptr, const int* __restrict__ doff,
                                int* __restrict__ dfill, int* __restrict__ perm) {
  int i = blockIdx.x * 256 + threadIdx.x;
  if (i < NN) {
    int deg = indptr[i + 1] - indptr[i];
    if (deg > 63) deg = 63;
    int pos = atomicAdd(&dfill[deg], 1);
    perm[doff[deg] + pos] = i;
  }
}

// ---------------- weight prep: concat Wl|Wr, split hi/lo, transpose -> BT[L][1024][256] ----------------

__global__ void prep_w(const float* __restrict__ Wl, const float* __restrict__ Wr,
                       unsigned short* __restrict__ BT) {
  int id = blockIdx.x * 256 + threadIdx.x;
  int l = id >> 17;
  int rem = id & 131071;
  int n = rem >> 7;
  int k = rem & 127;
  float v = (n < 512) ? Wl[((size_t)l * 128 + k) * 512 + n]
                      : Wr[((size_t)l * 128 + k) * 512 + (n - 512)];
  unsigned short h = f2bf(v);
  unsigned short lo = f2bf(v - b2f(h));
  size_t base = (size_t)(l * 1024 + n) * 256 + k;
  BT[base] = h;
  BT[base + 128] = lo;
}

// predictor weight prep
__global__ void prep_p(const float* __restrict__ p1W, const float* __restrict__ p2W,
                       unsigned short* __restrict__ BT1, unsigned short* __restrict__ BT2) {
  int id = blockIdx.x * 256 + threadIdx.x;
  if (id < 16384) {
    int n = id >> 7, k = id & 127;
    float v = p1W[k * 128 + n];
    unsigned short h = f2bf(v);
    BT1[n * 256 + k] = h;
    BT1[n * 256 + 128 + k] = f2bf(v - b2f(h));
  } else if (id < 24576) {
    int id2 = id - 16384;
    int n = id2 >> 7, k = id2 & 127;
    float v = p2W[k * 64 + n];
    unsigned short h = f2bf(v);
    BT2[n * 256 + k] = h;
    BT2[n * 256 + 128 + k] = f2bf(v - b2f(h));
  }
}

// ---------------- MFMA GEMM: A via global_load_lds double-buffer, B in registers (r14 proven) ----------------

#define MT64 ((NN + 63) / 64)

__global__ void __launch_bounds__(256)
mfma_gemm_pers(const unsigned short* __restrict__ AHL, const unsigned short* __restrict__ BT,
               const float* __restrict__ bias_l, const float* __restrict__ bias_r,
               unsigned short* __restrict__ XL, unsigned short* __restrict__ XR, int M) {
  __shared__ unsigned short sA[2 * 16384];

  int bid = blockIdx.x;
  int wg = (bid & 7) * 64 + (bid >> 3);
  int ntile = wg & 7;
  int mgroup = wg >> 3;
  int n0 = ntile * 128;

  int T = threadIdx.x;
  int wv = T >> 6, lane = T & 63;
  int r15 = lane & 15;
  int kslot = lane >> 4;
  int rx = lane & 7;

  int srow = T >> 5;
  int sw16 = (T & 31) ^ (srow & 7);

  bf16x8 wbh[4][2], wbl[4][2];
#pragma unroll
  for (int ks = 0; ks < 4; ++ks)
#pragma unroll
    for (int fw = 0; fw < 2; ++fw) {
      int row = n0 + wv * 32 + fw * 16 + r15;
      size_t idx = (size_t)row * 256 + ks * 32 + kslot * 8;
      wbh[ks][fw] = *(const bf16x8*)&BT[idx];
      wbl[ks][fw] = *(const bf16x8*)&BT[idx + 128];
    }

  unsigned short* Xout = (ntile < 4) ? XL : XR;
  const float* bias_sel = (ntile < 4) ? bias_l : bias_r;
  int ncol0 = (n0 & 511) + wv * 32;
  f32x4 bv[2];
#pragma unroll
  for (int fw = 0; fw < 2; ++fw)
    bv[fw] = *(const f32x4*)&bias_sel[ncol0 + fw * 16 + kslot * 4];

  int abase[4];
#pragma unroll
  for (int fa = 0; fa < 4; ++fa) abase[fa] = (fa * 16 + r15) * 256;

  {
    int m0 = mgroup * 64;
#pragma unroll
    for (int R = 0; R < 8; ++R) {
      int grow = m0 + R * 8 + srow;
      if (grow >= M) grow = M - 1;
      gload16(AHL + (size_t)grow * 256 + sw16 * 8, sA + R * 2048 + wv * 512);
    }
  }
  __syncthreads();

  int cur = 0;
  for (int mt = mgroup; mt < MT64; mt += 64) {
    int m0 = mt * 64;
    int nmt = mt + 64;
    if (nmt < MT64) {
      int nm0 = nmt * 64;
      int obuf = (cur ^ 1) * 16384;
#pragma unroll
      for (int R = 0; R < 8; ++R) {
        int grow = nm0 + R * 8 + srow;
        if (grow >= M) grow = M - 1;
        gload16(AHL + (size_t)grow * 256 + sw16 * 8, sA + obuf + R * 2048 + wv * 512);
      }
    }

    const unsigned short* Ab = sA + cur * 16384;
    f32x4 acc[2][4];
#pragma unroll
    for (int i = 0; i < 2; ++i)
#pragma unroll
      for (int j = 0; j < 4; ++j) acc[i][j] = (f32x4)0.f;

#pragma unroll
    for (int ks = 0; ks < 4; ++ks) {
      int shi = ((ks * 4 + kslot) ^ rx) * 8;
      int slo = ((16 + ks * 4 + kslot) ^ rx) * 8;
      bf16x8 fah[4], fal[4];
#pragma unroll
      for (int fa = 0; fa < 4; ++fa) {
        fah[fa] = *(const bf16x8*)&Ab[abase[fa] + shi];
        fal[fa] = *(const bf16x8*)&Ab[abase[fa] + slo];
      }
#pragma unroll
      for (int fw = 0; fw < 2; ++fw)
#pragma unroll
        for (int fa = 0; fa < 4; ++fa) {
          f32x4 c = acc[fw][fa];
          c = __builtin_amdgcn_mfma_f32_16x16x32_bf16(wbl[ks][fw], fah[fa], c, 0, 0, 0);
          c = __builtin_amdgcn_mfma_f32_16x16x32_bf16(wbh[ks][fw], fal[fa], c, 0, 0, 0);
          c = __builtin_amdgcn_mfma_f32_16x16x32_bf16(wbh[ks][fw], fah[fa], c, 0, 0, 0);
          acc[fw][fa] = c;
        }
    }

#pragma unroll
    for (int fa = 0; fa < 4; ++fa) {
      int row = m0 + fa * 16 + r15;
      if (row < M) {
#pragma unroll
        for (int fw = 0; fw < 2; ++fw) {
          int col = ncol0 + fw * 16 + kslot * 4;
          f32x4 v = acc[fw][fa];
          unsigned int u0 = (unsigned int)f2bf(v[0] + bv[fw][0]) |
                            ((unsigned int)f2bf(v[1] + bv[fw][1]) << 16);
          unsigned int u1 = (unsigned int)f2bf(v[2] + bv[fw][2]) |
                            ((unsigned int)f2bf(v[3] + bv[fw][3]) << 16);
          u32x2 o; o[0] = u0; o[1] = u1;
          *(u32x2*)&Xout[(size_t)row * 512 + col] = o;
        }
      }
    }
    __syncthreads();
    cur ^= 1;
  }
}

// ---------------- small MFMA GEMM (predictor): r17 proven ----------------

template <int NCOLS, int OSPLIT>
__global__ void __launch_bounds__(256)
mfma_gemm_small(const unsigned short* __restrict__ AHL, const unsigned short* __restrict__ BT,
                const float* __restrict__ bias, unsigned short* __restrict__ OutHL,
                float* __restrict__ OutF, int M) {
  __shared__ unsigned short sA[2 * 16384];
  constexpr int FW = NCOLS / 64;

  int T = threadIdx.x;
  int wv = T >> 6, lane = T & 63;
  int r15 = lane & 15;
  int kslot = lane >> 4;
  int rx = lane & 7;
  int srow = T >> 5;
  int sw16 = (T & 31) ^ (srow & 7);

  bf16x8 wbh[4][FW], wbl[4][FW];
#pragma unroll
  for (int ks = 0; ks < 4; ++ks)
#pragma unroll
    for (int fw = 0; fw < FW; ++fw) {
      int row = wv * (NCOLS / 4) + fw * 16 + r15;
      size_t idx = (size_t)row * 256 + ks * 32 + kslot * 8;
      wbh[ks][fw] = *(const bf16x8*)&BT[idx];
      wbl[ks][fw] = *(const bf16x8*)&BT[idx + 128];
    }

  int ncol0 = wv * (NCOLS / 4);
  f32x4 bv[FW];
#pragma unroll
  for (int fw = 0; fw < FW; ++fw)
    bv[fw] = *(const f32x4*)&bias[ncol0 + fw * 16 + kslot * 4];

  int abase[4];
#pragma unroll
  for (int fa = 0; fa < 4; ++fa) abase[fa] = (fa * 16 + r15) * 256;

  int mt0 = blockIdx.x;
  {
    int m0 = mt0 * 64;
#pragma unroll
    for (int R = 0; R < 8; ++R) {
      int grow = m0 + R * 8 + srow;
      if (grow >= M) grow = M - 1;
      gload16(AHL + (size_t)grow * 256 + sw16 * 8, sA + R * 2048 + wv * 512);
    }
  }
  __syncthreads();

  int cur = 0;
  for (int mt = mt0; mt < MT64; mt += gridDim.x) {
    int m0 = mt * 64;
    int nmt = mt + gridDim.x;
    if (nmt < MT64) {
      int nm0 = nmt * 64;
      int obuf = (cur ^ 1) * 16384;
#pragma unroll
      for (int R = 0; R < 8; ++R) {
        int grow = nm0 + R * 8 + srow;
        if (grow >= M) grow = M - 1;
        gload16(AHL + (size_t)grow * 256 + sw16 * 8, sA + obuf + R * 2048 + wv * 512);
      }
    }

    const unsigned short* Ab = sA + cur * 16384;
    f32x4 acc[FW][4];
#pragma unroll
    for (int i = 0; i < FW; ++i)
#pragma unroll
      for (int j = 0; j < 4; ++j) acc[i][j] = (f32x4)0.f;

#pragma unroll
    for (int ks = 0; ks < 4; ++ks) {
      int shi = ((ks * 4 + kslot) ^ rx) * 8;
      int slo = ((16 + ks * 4 + kslot) ^ rx) * 8;
      bf16x8 fah[4], fal[4];
#pragma unroll
      for (int fa = 0; fa < 4; ++fa) {
        fah[fa] = *(const bf16x8*)&Ab[abase[fa] + shi];
        fal[fa] = *(const bf16x8*)&Ab[abase[fa] + slo];
      }
#pragma unroll
      for (int fw = 0; fw < FW; ++fw)
#pragma unroll
        for (int fa = 0; fa < 4; ++fa) {
          f32x4 c = acc[fw][fa];
          c = __builtin_amdgcn_mfma_f32_16x16x32_bf16(wbl[ks][fw], fah[fa], c, 0, 0, 0);
          c = __builtin_amdgcn_mfma_f32_16x16x32_bf16(wbh[ks][fw], fal[fa], c, 0, 0, 0);
          c = __builtin_amdgcn_mfma_f32_16x16x32_bf16(wbh[ks][fw], fah[fa], c, 0, 0, 0);
          acc[fw][fa] = c;
        }
    }

#pragma unroll
    for (int fa = 0; fa < 4; ++fa) {
      int row = m0 + fa * 16 + r15;
      if (row < M) {
#pragma unroll
        for (int fw = 0; fw < FW; ++fw) {
          int col = ncol0 + fw * 16 + kslot * 4;
          f32x4 v = acc[fw][fa];
          float r0 = fmaxf(v[0] + bv[fw][0], 0.f);
          float r1 = fmaxf(v[1] + bv[fw][1], 0.f);
          float r2 = fmaxf(v[2] + bv[fw][2], 0.f);
          float r3 = fmaxf(v[3] + bv[fw][3], 0.f);
          if (OSPLIT) {
            unsigned short h0 = f2bf(r0), h1 = f2bf(r1), h2 = f2bf(r2), h3 = f2bf(r3);
            u32x2 hi, lo;
            hi[0] = (unsigned int)h0 | ((unsigned int)h1 << 16);
            hi[1] = (unsigned int)h2 | ((unsigned int)h3 << 16);
            lo[0] = (unsigned int)f2bf(r0 - b2f(h0)) | ((unsigned int)f2bf(r1 - b2f(h1)) << 16);
            lo[1] = (unsigned int)f2bf(r2 - b2f(h2)) | ((unsigned int)f2bf(r3 - b2f(h3)) << 16);
            *(u32x2*)&OutHL[(size_t)row * 256 + col] = hi;
            *(u32x2*)&OutHL[(size_t)row * 256 + 128 + col] = lo;
          } else {
            f32x4 o; o[0] = r0; o[1] = r1; o[2] = r2; o[3] = r3;
            *(f32x4*)&OutF[(size_t)row * NCOLS + col] = o;
          }
        }
      }
    }
    __syncthreads();
    cur ^= 1;
  }
}

// ---------------- fp32 tiled GEMM (embedding only) ----------------

template <int ACT, int SPLIT>
__global__ void __launch_bounds__(256)
gemm_bias(const float* __restrict__ A, const float* __restrict__ B,
          const float* __restrict__ bias, float* __restrict__ C,
          unsigned short* __restrict__ Chl,
          int M, int K, int Nc) {
  __shared__ float As[16][68];
  __shared__ float Bs[16][68];
  int tid = threadIdx.x;
  int tx = tid & 15, ty = tid >> 4;
  int m0 = blockIdx.y * 64;
  int n0 = blockIdx.x * 64;

  int arow = tid >> 2;
  int acol = (tid & 3) * 4;
  int brow = tid >> 4;
  int bcol = (tid & 15) * 4;

  float acc[4][4];
#pragma unroll
  for (int i = 0; i < 4; ++i)
#pragma unroll
    for (int j = 0; j < 4; ++j) acc[i][j] = 0.f;

  for (int k0 = 0; k0 < K; k0 += 16) {
    float4 av = make_float4(0.f, 0.f, 0.f, 0.f);
    if (m0 + arow < M) av = *(const float4*)&A[(size_t)(m0 + arow) * K + k0 + acol];
    As[acol + 0][arow] = av.x;
    As[acol + 1][arow] = av.y;
    As[acol + 2][arow] = av.z;
    As[acol + 3][arow] = av.w;
    float4 bvv = *(const float4*)&B[(size_t)(k0 + brow) * Nc + n0 + bcol];
    *(float4*)&Bs[brow][bcol] = bvv;
    __syncthreads();
#pragma unroll
    for (int k = 0; k < 16; ++k) {
      float4 a = *(const float4*)&As[k][ty * 4];
      float4 b = *(const float4*)&Bs[k][tx * 4];
      acc[0][0] += a.x * b.x; acc[0][1] += a.x * b.y; acc[0][2] += a.x * b.z; acc[0][3] += a.x * b.w;
      acc[1][0] += a.y * b.x; acc[1][1] += a.y * b.y; acc[1][2] += a.y * b.z; acc[1][3] += a.y * b.w;
      acc[2][0] += a.z * b.x; acc[2][1] += a.z * b.y; acc[2][2] += a.z * b.z; acc[2][3] += a.z * b.w;
      acc[3][0] += a.w * b.x; acc[3][1] += a.w * b.y; acc[3][2] += a.w * b.z; acc[3][3] += a.w * b.w;
    }
    __syncthreads();
  }

#pragma unroll
  for (int i = 0; i < 4; ++i) {
    int row = m0 + ty * 4 + i;
    if (row < M) {
#pragma unroll
      for (int j = 0; j < 4; ++j) {
        int col = n0 + tx * 4 + j;
        float v = acc[i][j] + bias[col];
        if (ACT) v = fmaxf(v, 0.f);
        C[(size_t)row * Nc + col] = v;
        if (SPLIT) {
          unsigned short hh = f2bf(v);
          Chl[(size_t)row * 256 + col] = hh;
          Chl[(size_t)row * 256 + 128 + col] = f2bf(v - b2f(hh));
        }
      }
    }
  }
}

// ---------------- GATv2 edge phase: r15 proven form + degree-sorted node permutation ----------------

__global__ void __launch_bounds__(256)
gat_aggregate(const unsigned short* __restrict__ xl, const unsigned short* __restrict__ xr,
              const int* __restrict__ indptr, const int* __restrict__ srcs,
              const int* __restrict__ perm,
              const float* __restrict__ att, const float* __restrict__ conv_bias,
              const float* __restrict__ h_in, float* __restrict__ h_out,
              unsigned short* __restrict__ o_hl, int write_f32) {
  int pos = blockIdx.x * 4 + (threadIdx.x >> 6);
  if (pos >= NN) return;
  int node = perm[pos];
  int lane = threadIdx.x & 63;
  int h = lane >> 4, g = lane & 15;
  int ch = h * 128 + g * 8;

  float a1[8], a2[8], xr8[8];
  {
    f32x4 t0 = *(const f32x4*)(att + ch);
    f32x4 t1 = *(const f32x4*)(att + ch + 4);
#pragma unroll
    for (int j = 0; j < 4; ++j) { a1[j] = 0.6f * t0[j]; a2[j] = 0.4f * t0[j]; }
#pragma unroll
    for (int j = 0; j < 4; ++j) { a1[4 + j] = 0.6f * t1[j]; a2[4 + j] = 0.4f * t1[j]; }
    u32x4 q = __builtin_nontemporal_load((const u32x4*)&xr[(size_t)node * 512 + ch]);
#pragma unroll
    for (int j = 0; j < 4; ++j) {
      xr8[2 * j] = bitf(q[j] << 16);
      xr8[2 * j + 1] = bitf(q[j] & 0xFFFF0000u);
    }
  }
  float base1 = 0.f;
#pragma unroll
  for (int j = 0; j < 8; ++j) base1 = fmaf(a1[j], xr8[j], base1);

  float acc[8];
#pragma unroll
  for (int j = 0; j < 8; ++j) acc[j] = 0.f;
  float s_run = 0.f;

  int beg = indptr[node];
  int deg = indptr[node + 1] - beg;

  for (int s0 = 0; s0 < deg; s0 += 8) {
    u32x4 q[8];
    int valid = deg - s0;
#pragma unroll
    for (int t = 0; t < 8; ++t) {
      int slot = s0 + t;
      int s = (slot < deg) ? srcs[beg + slot] : srcs[beg];
      q[t] = *(const u32x4*)&xl[(size_t)s * 512 + ch];
    }
    float xf[8][8];
#pragma unroll
    for (int t = 0; t < 8; ++t)
#pragma unroll
      for (int j = 0; j < 4; ++j) {
        xf[t][2 * j] = bitf(q[t][j] << 16);
        xf[t][2 * j + 1] = bitf(q[t][j] & 0xFFFF0000u);
      }
    float p[8];
#pragma unroll
    for (int t = 0; t < 8; ++t) {
      float pp = base1;
#pragma unroll
      for (int j = 0; j < 8; ++j) {
        pp = fmaf(a1[j], xf[t][j], pp);
        pp = fmaf(a2[j], fabsf(xf[t][j] + xr8[j]), pp);
      }
      p[t] = pp;
    }
#pragma unroll
    for (int t = 0; t < 8; ++t) {
#pragma unroll
      for (int off = 1; off < 16; off <<= 1) p[t] += __shfl_xor(p[t], off);
    }
    float w[8];
#pragma unroll
    for (int t = 0; t < 8; ++t)
      w[t] = (t < valid) ? __expf(p[t]) : 0.f;
#pragma unroll
    for (int t = 0; t < 8; ++t) s_run += w[t];
#pragma unroll
    for (int j = 0; j < 8; ++j) {
      float v = acc[j];
#pragma unroll
      for (int t = 0; t < 8; ++t) v = fmaf(w[t], xf[t][j], v);
      acc[j] = v;
    }
  }

  float inv = 1.f / fmaxf(s_run, 1e-16f);
  float v[8];
#pragma unroll
  for (int j = 0; j < 8; ++j) v[j] = acc[j] * inv;
#pragma unroll
  for (int j = 0; j < 8; ++j) v[j] += __shfl_xor(v[j], 16);
#pragma unroll
  for (int j = 0; j < 8; ++j) v[j] += __shfl_xor(v[j], 32);

  if (h == 0) {
    int c0 = g * 8;
    const float* hip_ = h_in + (size_t)node * 128 + c0;
    f32x4 hi0 = __builtin_nontemporal_load((const f32x4*)hip_);
    f32x4 hi1 = __builtin_nontemporal_load((const f32x4*)(hip_ + 4));
    f32x4 cb0 = *(const f32x4*)(conv_bias + c0);
    f32x4 cb1 = *(const f32x4*)(conv_bias + c0 + 4);
    float rr[8];
#pragma unroll
    for (int j = 0; j < 4; ++j) rr[j] = fmaxf(fmaf(v[j], 0.25f, cb0[j] + hi0[j]), 0.f);
#pragma unroll
    for (int j = 0; j < 4; ++j) rr[4 + j] = fmaxf(fmaf(v[4 + j], 0.25f, cb1[j] + hi1[j]), 0.f);
    if (write_f32) {
      f32x4 o0, o1;
#pragma unroll
      for (int j = 0; j < 4; ++j) { o0[j] = rr[j]; o1[j] = rr[4 + j]; }
      float* hop = h_out + (size_t)node * 128 + c0;
      __builtin_nontemporal_store(o0, (f32x4*)hop);
      __builtin_nontemporal_store(o1, (f32x4*)(hop + 4));
    }
    {
      ushort8 hv, lv;
#pragma unroll
      for (int j = 0; j < 8; ++j) {
        unsigned short hh = f2bf(rr[j]);
        hv[j] = hh;
        lv[j] = f2bf(rr[j] - b2f(hh));
      }
      __builtin_nontemporal_store(hv, (ushort8*)&o_hl[(size_t)node * 256 + c0]);
      __builtin_nontemporal_store(lv, (ushort8*)&o_hl[(size_t)node * 256 + 128 + c0]);
    }
  }
}

// ---------------- final: score = clip(z2 @ p3_W + p3_b) ----------------

__global__ void __launch_bounds__(256)
predictor_final(const float* __restrict__ z2, const float* __restrict__ w3,
                const float* __restrict__ b3, float* __restrict__ out, int n) {
  int node = (blockIdx.x << 2) + (threadIdx.x >> 6);
  int lane = threadIdx.x & 63;
  if (node >= n) return;
  float v = z2[(size_t)node * 64 + lane] * w3[lane];
#pragma unroll
  for (int off = 32; off > 0; off >>= 1) v += __shfl_xor(v, off);
  if (lane == 0) {
    float s = v + b3[0];
    s = fminf(fmaxf(s, -15.f), 15.f);
    out[node] = s;
  }
}

// ---------------- launch ----------------

extern "C" void kernel_launch(void* const* d_in, const int* in_sizes, int n_in,
                              void* d_out, int out_size, void* d_ws, size_t ws_size,
                              hipStream_t stream) {
  const float* x     = (const float*)d_in[0];
  const int*   ei    = (const int*)d_in[1];
  const float* emb_W = (const float*)d_in[3];
  const float* emb_b = (const float*)d_in[4];
  const float* Wl    = (const float*)d_in[5];
  const float* bl    = (const float*)d_in[6];
  const float* Wr    = (const float*)d_in[7];
  const float* br    = (const float*)d_in[8];
  const float* att   = (const float*)d_in[9];
  const float* cbias = (const float*)d_in[10];
  const float* p1W   = (const float*)d_in[11];
  const float* p1b   = (const float*)d_in[12];
  const float* p2W   = (const float*)d_in[13];
  const float* p2b   = (const float*)d_in[14];
  const float* p3W   = (const float*)d_in[15];
  const float* p3b   = (const float*)d_in[16];
  float* out = (float*)d_out;

  char* ws = (char*)d_ws;
  size_t o = 0;
  float* h0 = (float*)(ws + o); o += (size_t)NN * 128 * 4;
  float* h1 = (float*)(ws + o); o += (size_t)NN * 128 * 4;
  unsigned short* h_hl = (unsigned short*)(ws + o); o += (size_t)NN * 256 * 2;
  unsigned short* xl_bf = (unsigned short*)(ws + o); o += (size_t)NN * 512 * 2;
  unsigned short* xr_bf = (unsigned short*)(ws + o); o += (size_t)NN * 512 * 2;
  unsigned short* BT = (unsigned short*)(ws + o); o += (size_t)LAYERS * 1024 * 256 * 2;
  unsigned short* BT1 = (unsigned short*)(ws + o); o += (size_t)128 * 256 * 2;
  unsigned short* BT2 = (unsigned short*)(ws + o); o += (size_t)64 * 256 * 2;
  int* indptr = (int*)(ws + o); o += (((size_t)(NN + 1) * 4) + 255) / 256 * 256;
  int* counts = (int*)(ws + o); o += (((size_t)NN * 4) + 255) / 256 * 256;
  int* perm = (int*)(ws + o); o += (size_t)NN * 4;
  int* bsum = (int*)(ws + o); o += 256;
  int* boff = (int*)(ws + o); o += 256;
  int* dbins = (int*)(ws + o); o += 256;
  int* doff = (int*)(ws + o); o += 256;
  int* dfill = (int*)(ws + o); o += 256;
  int* srcs   = (int*)(ws + o); o += (size_t)NE * 4;

  const int* esrc = ei;
  const int* edst = ei + NE;
  int nb = (NN + 1023) / 1024;

  // CSR build (parallel 3-kernel scan)
  hipMemsetAsync(counts, 0, (size_t)NN * 4, stream);
  hipMemsetAsync(dbins, 0, 256, stream);
  hipMemsetAsync(dfill, 0, 256, stream);
  hist_kernel<<<(NE + 255) / 256, 256, 0, stream>>>(edst, counts, NE);
  scan1_kernel<<<nb, 1024, 0, stream>>>(counts, indptr, bsum, NN);
  scan2_kernel<<<1, 64, 0, stream>>>(bsum, boff, nb, indptr, NN);
  scan3_kernel<<<nb, 1024, 0, stream>>>(indptr, boff, NN);
  hipMemsetAsync(counts, 0, (size_t)NN * 4, stream);
  scatter_kernel<<<(NE + 255) / 256, 256, 0, stream>>>(esrc, edst, indptr, counts, srcs, NE);

  // degree-sorted permutation for gat scheduling
  dhist_kernel<<<(NN + 255) / 256, 256, 0, stream>>>(indptr, dbins);
  dscan_kernel<<<1, 64, 0, stream>>>(dbins, doff);
  dscatter_kernel<<<(NN + 255) / 256, 256, 0, stream>>>(indptr, doff, dfill, perm);

  // weight prep
  prep_w<<<(LAYERS * 1024 * 128) / 256, 256, 0, stream>>>(Wl, Wr, BT);
  prep_p<<<96, 256, 0, stream>>>(p1W, p2W, BT1, BT2);

  // embedding (fp32) + hi/lo split fused
  gemm_bias<1, 1><<<dim3(2, (NN + 63) / 64), 256, 0, stream>>>(
      x, emb_W, emb_b, h0, h_hl, NN, 64, 128);

  float* hc = h0;
  float* hn = h1;
  for (int l = 0; l < LAYERS; ++l) {
    mfma_gemm_pers<<<512, 256, 0, stream>>>(
        h_hl, BT + (size_t)l * 1024 * 256,
        bl + (size_t)l * 512, br + (size_t)l * 512, xl_bf, xr_bf, NN);
    gat_aggregate<<<(NN + 3) / 4, 256, 0, stream>>>(
        xl_bf, xr_bf, indptr, srcs, perm, att + (size_t)l * 512, cbias + (size_t)l * 128,
        hc, hn, h_hl, (l < LAYERS - 1) ? 1 : 0);
    float* t = hc; hc = hn; hn = t;
  }

  // predictor: p1/p2 via MFMA, p3 fp32
  unsigned short* z1_hl = xl_bf;
  float* z2f = (float*)xr_bf;
  mfma_gemm_small<128, 1><<<512, 256, 0, stream>>>(h_hl, BT1, p1b, z1_hl, (float*)0, NN);
  mfma_gemm_small<64, 0><<<512, 256, 0, stream>>>(z1_hl, BT2, p2b, (unsigned short*)0, z2f, NN);
  predictor_final<<<(NN + 3) / 4, 256, 0, stream>>>(z2f, p3W, p3b, out, NN);
}

// Round 21
// 757.530 us; speedup vs baseline: 1.2694x; 1.2694x over previous
//
#include <hip/hip_runtime.h>
#include <math.h>

#define NN 50000
#define NE 800000
#define F_IN 64
#define HID 128
#define HEADS 4
#define LAYERS 3

typedef __attribute__((ext_vector_type(8))) short bf16x8;
typedef __attribute__((ext_vector_type(8))) unsigned short ushort8;
typedef __attribute__((ext_vector_type(4))) float f32x4;
typedef __attribute__((ext_vector_type(4))) unsigned int u32x4;
typedef __attribute__((ext_vector_type(2))) unsigned int u32x2;

__device__ __forceinline__ float b2f(unsigned short u) {
  return __builtin_bit_cast(float, ((unsigned int)u) << 16);
}
__device__ __forceinline__ unsigned short f2bf(float f) {
  unsigned int u = __builtin_bit_cast(unsigned int, f);
  u = (u + 0x7FFFu + ((u >> 16) & 1u)) >> 16;
  return (unsigned short)u;
}
__device__ __forceinline__ float bitf(unsigned int u) {
  return __builtin_bit_cast(float, u);
}

__device__ __forceinline__ void gload16(const void* g, void* l) {
  __builtin_amdgcn_global_load_lds(
      (const __attribute__((address_space(1))) unsigned int*)g,
      (__attribute__((address_space(3))) unsigned int*)l, 16, 0, 0);
}

// ---------------- CSR build ----------------

__global__ void hist_kernel(const int* __restrict__ dst, int* __restrict__ counts, int E) {
  int e = blockIdx.x * blockDim.x + threadIdx.x;
  if (e < E) atomicAdd(&counts[dst[e]], 1);
}

__global__ void scan1_kernel(const int* __restrict__ counts, int* __restrict__ indptr,
                             int* __restrict__ bsum, int n) {
  __shared__ int buf[1024];
  int tid = threadIdx.x;
  int i = blockIdx.x * 1024 + tid;
  int v = (i < n) ? counts[i] : 0;
  buf[tid] = v;
  __syncthreads();
  for (int off = 1; off < 1024; off <<= 1) {
    int t = (tid >= off) ? buf[tid - off] : 0;
    __syncthreads();
    buf[tid] += t;
    __syncthreads();
  }
  if (i < n) indptr[i] = buf[tid] - v;
  if (tid == 1023) bsum[blockIdx.x] = buf[1023];
}

__global__ void scan2_kernel(int* __restrict__ bsum, int* __restrict__ boff,
                             int nb, int* __restrict__ indptr, int n) {
  if (threadIdx.x == 0 && blockIdx.x == 0) {
    int s = 0;
    for (int c = 0; c < nb; ++c) { boff[c] = s; s += bsum[c]; }
    indptr[n] = s;
  }
}

__global__ void scan3_kernel(int* __restrict__ indptr, const int* __restrict__ boff, int n) {
  int i = blockIdx.x * 1024 + threadIdx.x;
  if (i < n) indptr[i] += boff[blockIdx.x];
}

__global__ void scatter_kernel(const int* __restrict__ src, const int* __restrict__ dst,
                               const int* __restrict__ indptr, int* __restrict__ fill,
                               int* __restrict__ srcs, int E) {
  int e = blockIdx.x * blockDim.x + threadIdx.x;
  if (e < E) {
    int d = dst[e];
    int pos = atomicAdd(&fill[d], 1);
    srcs[indptr[d] + pos] = src[e];
  }
}

// ---------------- weight prep: concat Wl|Wr, split hi/lo, transpose -> BT[L][1024][256] ----------------

__global__ void prep_w(const float* __restrict__ Wl, const float* __restrict__ Wr,
                       unsigned short* __restrict__ BT) {
  int id = blockIdx.x * 256 + threadIdx.x;
  int l = id >> 17;
  int rem = id & 131071;
  int n = rem >> 7;
  int k = rem & 127;
  float v = (n < 512) ? Wl[((size_t)l * 128 + k) * 512 + n]
                      : Wr[((size_t)l * 128 + k) * 512 + (n - 512)];
  unsigned short h = f2bf(v);
  unsigned short lo = f2bf(v - b2f(h));
  size_t base = (size_t)(l * 1024 + n) * 256 + k;
  BT[base] = h;
  BT[base + 128] = lo;
}

// predictor weight prep
__global__ void prep_p(const float* __restrict__ p1W, const float* __restrict__ p2W,
                       unsigned short* __restrict__ BT1, unsigned short* __restrict__ BT2) {
  int id = blockIdx.x * 256 + threadIdx.x;
  if (id < 16384) {
    int n = id >> 7, k = id & 127;
    float v = p1W[k * 128 + n];
    unsigned short h = f2bf(v);
    BT1[n * 256 + k] = h;
    BT1[n * 256 + 128 + k] = f2bf(v - b2f(h));
  } else if (id < 24576) {
    int id2 = id - 16384;
    int n = id2 >> 7, k = id2 & 127;
    float v = p2W[k * 64 + n];
    unsigned short h = f2bf(v);
    BT2[n * 256 + k] = h;
    BT2[n * 256 + 128 + k] = f2bf(v - b2f(h));
  }
}

// ---------------- MFMA GEMM: A via global_load_lds double-buffer, B in registers (r14 proven) ----------------

#define MT64 ((NN + 63) / 64)

__global__ void __launch_bounds__(256)
mfma_gemm_pers(const unsigned short* __restrict__ AHL, const unsigned short* __restrict__ BT,
               const float* __restrict__ bias_l, const float* __restrict__ bias_r,
               unsigned short* __restrict__ XL, unsigned short* __restrict__ XR, int M) {
  __shared__ unsigned short sA[2 * 16384];

  int bid = blockIdx.x;
  int wg = (bid & 7) * 64 + (bid >> 3);
  int ntile = wg & 7;
  int mgroup = wg >> 3;
  int n0 = ntile * 128;

  int T = threadIdx.x;
  int wv = T >> 6, lane = T & 63;
  int r15 = lane & 15;
  int kslot = lane >> 4;
  int rx = lane & 7;

  int srow = T >> 5;
  int sw16 = (T & 31) ^ (srow & 7);

  bf16x8 wbh[4][2], wbl[4][2];
#pragma unroll
  for (int ks = 0; ks < 4; ++ks)
#pragma unroll
    for (int fw = 0; fw < 2; ++fw) {
      int row = n0 + wv * 32 + fw * 16 + r15;
      size_t idx = (size_t)row * 256 + ks * 32 + kslot * 8;
      wbh[ks][fw] = *(const bf16x8*)&BT[idx];
      wbl[ks][fw] = *(const bf16x8*)&BT[idx + 128];
    }

  unsigned short* Xout = (ntile < 4) ? XL : XR;
  const float* bias_sel = (ntile < 4) ? bias_l : bias_r;
  int ncol0 = (n0 & 511) + wv * 32;
  f32x4 bv[2];
#pragma unroll
  for (int fw = 0; fw < 2; ++fw)
    bv[fw] = *(const f32x4*)&bias_sel[ncol0 + fw * 16 + kslot * 4];

  int abase[4];
#pragma unroll
  for (int fa = 0; fa < 4; ++fa) abase[fa] = (fa * 16 + r15) * 256;

  {
    int m0 = mgroup * 64;
#pragma unroll
    for (int R = 0; R < 8; ++R) {
      int grow = m0 + R * 8 + srow;
      if (grow >= M) grow = M - 1;
      gload16(AHL + (size_t)grow * 256 + sw16 * 8, sA + R * 2048 + wv * 512);
    }
  }
  __syncthreads();

  int cur = 0;
  for (int mt = mgroup; mt < MT64; mt += 64) {
    int m0 = mt * 64;
    int nmt = mt + 64;
    if (nmt < MT64) {
      int nm0 = nmt * 64;
      int obuf = (cur ^ 1) * 16384;
#pragma unroll
      for (int R = 0; R < 8; ++R) {
        int grow = nm0 + R * 8 + srow;
        if (grow >= M) grow = M - 1;
        gload16(AHL + (size_t)grow * 256 + sw16 * 8, sA + obuf + R * 2048 + wv * 512);
      }
    }

    const unsigned short* Ab = sA + cur * 16384;
    f32x4 acc[2][4];
#pragma unroll
    for (int i = 0; i < 2; ++i)
#pragma unroll
      for (int j = 0; j < 4; ++j) acc[i][j] = (f32x4)0.f;

#pragma unroll
    for (int ks = 0; ks < 4; ++ks) {
      int shi = ((ks * 4 + kslot) ^ rx) * 8;
      int slo = ((16 + ks * 4 + kslot) ^ rx) * 8;
      bf16x8 fah[4], fal[4];
#pragma unroll
      for (int fa = 0; fa < 4; ++fa) {
        fah[fa] = *(const bf16x8*)&Ab[abase[fa] + shi];
        fal[fa] = *(const bf16x8*)&Ab[abase[fa] + slo];
      }
#pragma unroll
      for (int fw = 0; fw < 2; ++fw)
#pragma unroll
        for (int fa = 0; fa < 4; ++fa) {
          f32x4 c = acc[fw][fa];
          c = __builtin_amdgcn_mfma_f32_16x16x32_bf16(wbl[ks][fw], fah[fa], c, 0, 0, 0);
          c = __builtin_amdgcn_mfma_f32_16x16x32_bf16(wbh[ks][fw], fal[fa], c, 0, 0, 0);
          c = __builtin_amdgcn_mfma_f32_16x16x32_bf16(wbh[ks][fw], fah[fa], c, 0, 0, 0);
          acc[fw][fa] = c;
        }
    }

#pragma unroll
    for (int fa = 0; fa < 4; ++fa) {
      int row = m0 + fa * 16 + r15;
      if (row < M) {
#pragma unroll
        for (int fw = 0; fw < 2; ++fw) {
          int col = ncol0 + fw * 16 + kslot * 4;
          f32x4 v = acc[fw][fa];
          unsigned int u0 = (unsigned int)f2bf(v[0] + bv[fw][0]) |
                            ((unsigned int)f2bf(v[1] + bv[fw][1]) << 16);
          unsigned int u1 = (unsigned int)f2bf(v[2] + bv[fw][2]) |
                            ((unsigned int)f2bf(v[3] + bv[fw][3]) << 16);
          u32x2 o; o[0] = u0; o[1] = u1;
          *(u32x2*)&Xout[(size_t)row * 512 + col] = o;
        }
      }
    }
    __syncthreads();
    cur ^= 1;
  }
}

// ---------------- small MFMA GEMM (predictor): r17 proven ----------------

template <int NCOLS, int OSPLIT>
__global__ void __launch_bounds__(256)
mfma_gemm_small(const unsigned short* __restrict__ AHL, const unsigned short* __restrict__ BT,
                const float* __restrict__ bias, unsigned short* __restrict__ OutHL,
                float* __restrict__ OutF, int M) {
  __shared__ unsigned short sA[2 * 16384];
  constexpr int FW = NCOLS / 64;

  int T = threadIdx.x;
  int wv = T >> 6, lane = T & 63;
  int r15 = lane & 15;
  int kslot = lane >> 4;
  int rx = lane & 7;
  int srow = T >> 5;
  int sw16 = (T & 31) ^ (srow & 7);

  bf16x8 wbh[4][FW], wbl[4][FW];
#pragma unroll
  for (int ks = 0; ks < 4; ++ks)
#pragma unroll
    for (int fw = 0; fw < FW; ++fw) {
      int row = wv * (NCOLS / 4) + fw * 16 + r15;
      size_t idx = (size_t)row * 256 + ks * 32 + kslot * 8;
      wbh[ks][fw] = *(const bf16x8*)&BT[idx];
      wbl[ks][fw] = *(const bf16x8*)&BT[idx + 128];
    }

  int ncol0 = wv * (NCOLS / 4);
  f32x4 bv[FW];
#pragma unroll
  for (int fw = 0; fw < FW; ++fw)
    bv[fw] = *(const f32x4*)&bias[ncol0 + fw * 16 + kslot * 4];

  int abase[4];
#pragma unroll
  for (int fa = 0; fa < 4; ++fa) abase[fa] = (fa * 16 + r15) * 256;

  int mt0 = blockIdx.x;
  {
    int m0 = mt0 * 64;
#pragma unroll
    for (int R = 0; R < 8; ++R) {
      int grow = m0 + R * 8 + srow;
      if (grow >= M) grow = M - 1;
      gload16(AHL + (size_t)grow * 256 + sw16 * 8, sA + R * 2048 + wv * 512);
    }
  }
  __syncthreads();

  int cur = 0;
  for (int mt = mt0; mt < MT64; mt += gridDim.x) {
    int m0 = mt * 64;
    int nmt = mt + gridDim.x;
    if (nmt < MT64) {
      int nm0 = nmt * 64;
      int obuf = (cur ^ 1) * 16384;
#pragma unroll
      for (int R = 0; R < 8; ++R) {
        int grow = nm0 + R * 8 + srow;
        if (grow >= M) grow = M - 1;
        gload16(AHL + (size_t)grow * 256 + sw16 * 8, sA + obuf + R * 2048 + wv * 512);
      }
    }

    const unsigned short* Ab = sA + cur * 16384;
    f32x4 acc[FW][4];
#pragma unroll
    for (int i = 0; i < FW; ++i)
#pragma unroll
      for (int j = 0; j < 4; ++j) acc[i][j] = (f32x4)0.f;

#pragma unroll
    for (int ks = 0; ks < 4; ++ks) {
      int shi = ((ks * 4 + kslot) ^ rx) * 8;
      int slo = ((16 + ks * 4 + kslot) ^ rx) * 8;
      bf16x8 fah[4], fal[4];
#pragma unroll
      for (int fa = 0; fa < 4; ++fa) {
        fah[fa] = *(const bf16x8*)&Ab[abase[fa] + shi];
        fal[fa] = *(const bf16x8*)&Ab[abase[fa] + slo];
      }
#pragma unroll
      for (int fw = 0; fw < FW; ++fw)
#pragma unroll
        for (int fa = 0; fa < 4; ++fa) {
          f32x4 c = acc[fw][fa];
          c = __builtin_amdgcn_mfma_f32_16x16x32_bf16(wbl[ks][fw], fah[fa], c, 0, 0, 0);
          c = __builtin_amdgcn_mfma_f32_16x16x32_bf16(wbh[ks][fw], fal[fa], c, 0, 0, 0);
          c = __builtin_amdgcn_mfma_f32_16x16x32_bf16(wbh[ks][fw], fah[fa], c, 0, 0, 0);
          acc[fw][fa] = c;
        }
    }

#pragma unroll
    for (int fa = 0; fa < 4; ++fa) {
      int row = m0 + fa * 16 + r15;
      if (row < M) {
#pragma unroll
        for (int fw = 0; fw < FW; ++fw) {
          int col = ncol0 + fw * 16 + kslot * 4;
          f32x4 v = acc[fw][fa];
          float r0 = fmaxf(v[0] + bv[fw][0], 0.f);
          float r1 = fmaxf(v[1] + bv[fw][1], 0.f);
          float r2 = fmaxf(v[2] + bv[fw][2], 0.f);
          float r3 = fmaxf(v[3] + bv[fw][3], 0.f);
          if (OSPLIT) {
            unsigned short h0 = f2bf(r0), h1 = f2bf(r1), h2 = f2bf(r2), h3 = f2bf(r3);
            u32x2 hi, lo;
            hi[0] = (unsigned int)h0 | ((unsigned int)h1 << 16);
            hi[1] = (unsigned int)h2 | ((unsigned int)h3 << 16);
            lo[0] = (unsigned int)f2bf(r0 - b2f(h0)) | ((unsigned int)f2bf(r1 - b2f(h1)) << 16);
            lo[1] = (unsigned int)f2bf(r2 - b2f(h2)) | ((unsigned int)f2bf(r3 - b2f(h3)) << 16);
            *(u32x2*)&OutHL[(size_t)row * 256 + col] = hi;
            *(u32x2*)&OutHL[(size_t)row * 256 + 128 + col] = lo;
          } else {
            f32x4 o; o[0] = r0; o[1] = r1; o[2] = r2; o[3] = r3;
            *(f32x4*)&OutF[(size_t)row * NCOLS + col] = o;
          }
        }
      }
    }
    __syncthreads();
    cur ^= 1;
  }
}

// ---------------- fp32 tiled GEMM (embedding only) ----------------

template <int ACT, int SPLIT>
__global__ void __launch_bounds__(256)
gemm_bias(const float* __restrict__ A, const float* __restrict__ B,
          const float* __restrict__ bias, float* __restrict__ C,
          unsigned short* __restrict__ Chl,
          int M, int K, int Nc) {
  __shared__ float As[16][68];
  __shared__ float Bs[16][68];
  int tid = threadIdx.x;
  int tx = tid & 15, ty = tid >> 4;
  int m0 = blockIdx.y * 64;
  int n0 = blockIdx.x * 64;

  int arow = tid >> 2;
  int acol = (tid & 3) * 4;
  int brow = tid >> 4;
  int bcol = (tid & 15) * 4;

  float acc[4][4];
#pragma unroll
  for (int i = 0; i < 4; ++i)
#pragma unroll
    for (int j = 0; j < 4; ++j) acc[i][j] = 0.f;

  for (int k0 = 0; k0 < K; k0 += 16) {
    float4 av = make_float4(0.f, 0.f, 0.f, 0.f);
    if (m0 + arow < M) av = *(const float4*)&A[(size_t)(m0 + arow) * K + k0 + acol];
    As[acol + 0][arow] = av.x;
    As[acol + 1][arow] = av.y;
    As[acol + 2][arow] = av.z;
    As[acol + 3][arow] = av.w;
    float4 bvv = *(const float4*)&B[(size_t)(k0 + brow) * Nc + n0 + bcol];
    *(float4*)&Bs[brow][bcol] = bvv;
    __syncthreads();
#pragma unroll
    for (int k = 0; k < 16; ++k) {
      float4 a = *(const float4*)&As[k][ty * 4];
      float4 b = *(const float4*)&Bs[k][tx * 4];
      acc[0][0] += a.x * b.x; acc[0][1] += a.x * b.y; acc[0][2] += a.x * b.z; acc[0][3] += a.x * b.w;
      acc[1][0] += a.y * b.x; acc[1][1] += a.y * b.y; acc[1][2] += a.y * b.z; acc[1][3] += a.y * b.w;
      acc[2][0] += a.z * b.x; acc[2][1] += a.z * b.y; acc[2][2] += a.z * b.z; acc[2][3] += a.z * b.w;
      acc[3][0] += a.w * b.x; acc[3][1] += a.w * b.y; acc[3][2] += a.w * b.z; acc[3][3] += a.w * b.w;
    }
    __syncthreads();
  }

#pragma unroll
  for (int i = 0; i < 4; ++i) {
    int row = m0 + ty * 4 + i;
    if (row < M) {
#pragma unroll
      for (int j = 0; j < 4; ++j) {
        int col = n0 + tx * 4 + j;
        float v = acc[i][j] + bias[col];
        if (ACT) v = fmaxf(v, 0.f);
        C[(size_t)row * Nc + col] = v;
        if (SPLIT) {
          unsigned short hh = f2bf(v);
          Chl[(size_t)row * 256 + col] = hh;
          Chl[(size_t)row * 256 + 128 + col] = f2bf(v - b2f(hh));
        }
      }
    }
  }
}

// ---------------- GATv2 edge phase: 1 wave per node, 8 edges in flight (r15/r17 proven form) ----------------

__global__ void __launch_bounds__(256)
gat_aggregate(const unsigned short* __restrict__ xl, const unsigned short* __restrict__ xr,
              const int* __restrict__ indptr, const int* __restrict__ srcs,
              const float* __restrict__ att, const float* __restrict__ conv_bias,
              const float* __restrict__ h_in, float* __restrict__ h_out,
              unsigned short* __restrict__ o_hl, int write_f32) {
  int node = blockIdx.x * 4 + (threadIdx.x >> 6);
  if (node >= NN) return;
  int lane = threadIdx.x & 63;
  int h = lane >> 4, g = lane & 15;
  int ch = h * 128 + g * 8;

  float a1[8], a2[8], xr8[8];
  {
    f32x4 t0 = *(const f32x4*)(att + ch);
    f32x4 t1 = *(const f32x4*)(att + ch + 4);
#pragma unroll
    for (int j = 0; j < 4; ++j) { a1[j] = 0.6f * t0[j]; a2[j] = 0.4f * t0[j]; }
#pragma unroll
    for (int j = 0; j < 4; ++j) { a1[4 + j] = 0.6f * t1[j]; a2[4 + j] = 0.4f * t1[j]; }
    u32x4 q = __builtin_nontemporal_load((const u32x4*)&xr[(size_t)node * 512 + ch]);
#pragma unroll
    for (int j = 0; j < 4; ++j) {
      xr8[2 * j] = bitf(q[j] << 16);
      xr8[2 * j + 1] = bitf(q[j] & 0xFFFF0000u);
    }
  }
  float base1 = 0.f;
#pragma unroll
  for (int j = 0; j < 8; ++j) base1 = fmaf(a1[j], xr8[j], base1);

  float acc[8];
#pragma unroll
  for (int j = 0; j < 8; ++j) acc[j] = 0.f;
  float s_run = 0.f;

  int beg = indptr[node];
  int deg = indptr[node + 1] - beg;

  for (int s0 = 0; s0 < deg; s0 += 8) {
    u32x4 q[8];
    int valid = deg - s0;
#pragma unroll
    for (int t = 0; t < 8; ++t) {
      int slot = s0 + t;
      int s = (slot < deg) ? srcs[beg + slot] : srcs[beg];
      q[t] = *(const u32x4*)&xl[(size_t)s * 512 + ch];
    }
    float xf[8][8];
#pragma unroll
    for (int t = 0; t < 8; ++t)
#pragma unroll
      for (int j = 0; j < 4; ++j) {
        xf[t][2 * j] = bitf(q[t][j] << 16);
        xf[t][2 * j + 1] = bitf(q[t][j] & 0xFFFF0000u);
      }
    float p[8];
#pragma unroll
    for (int t = 0; t < 8; ++t) {
      float pp = base1;
#pragma unroll
      for (int j = 0; j < 8; ++j) {
        pp = fmaf(a1[j], xf[t][j], pp);
        pp = fmaf(a2[j], fabsf(xf[t][j] + xr8[j]), pp);
      }
      p[t] = pp;
    }
#pragma unroll
    for (int t = 0; t < 8; ++t) {
#pragma unroll
      for (int off = 1; off < 16; off <<= 1) p[t] += __shfl_xor(p[t], off);
    }
    float w[8];
#pragma unroll
    for (int t = 0; t < 8; ++t)
      w[t] = (t < valid) ? __expf(p[t]) : 0.f;
#pragma unroll
    for (int t = 0; t < 8; ++t) s_run += w[t];
#pragma unroll
    for (int j = 0; j < 8; ++j) {
      float v = acc[j];
#pragma unroll
      for (int t = 0; t < 8; ++t) v = fmaf(w[t], xf[t][j], v);
      acc[j] = v;
    }
  }

  float inv = 1.f / fmaxf(s_run, 1e-16f);
  float v[8];
#pragma unroll
  for (int j = 0; j < 8; ++j) v[j] = acc[j] * inv;
#pragma unroll
  for (int j = 0; j < 8; ++j) v[j] += __shfl_xor(v[j], 16);
#pragma unroll
  for (int j = 0; j < 8; ++j) v[j] += __shfl_xor(v[j], 32);

  if (h == 0) {
    int c0 = g * 8;
    const float* hip_ = h_in + (size_t)node * 128 + c0;
    f32x4 hi0 = __builtin_nontemporal_load((const f32x4*)hip_);
    f32x4 hi1 = __builtin_nontemporal_load((const f32x4*)(hip_ + 4));
    f32x4 cb0 = *(const f32x4*)(conv_bias + c0);
    f32x4 cb1 = *(const f32x4*)(conv_bias + c0 + 4);
    float rr[8];
#pragma unroll
    for (int j = 0; j < 4; ++j) rr[j] = fmaxf(fmaf(v[j], 0.25f, cb0[j] + hi0[j]), 0.f);
#pragma unroll
    for (int j = 0; j < 4; ++j) rr[4 + j] = fmaxf(fmaf(v[4 + j], 0.25f, cb1[j] + hi1[j]), 0.f);
    if (write_f32) {
      f32x4 o0, o1;
#pragma unroll
      for (int j = 0; j < 4; ++j) { o0[j] = rr[j]; o1[j] = rr[4 + j]; }
      float* hop = h_out + (size_t)node * 128 + c0;
      __builtin_nontemporal_store(o0, (f32x4*)hop);
      __builtin_nontemporal_store(o1, (f32x4*)(hop + 4));
    }
    {
      ushort8 hv, lv;
#pragma unroll
      for (int j = 0; j < 8; ++j) {
        unsigned short hh = f2bf(rr[j]);
        hv[j] = hh;
        lv[j] = f2bf(rr[j] - b2f(hh));
      }
      __builtin_nontemporal_store(hv, (ushort8*)&o_hl[(size_t)node * 256 + c0]);
      __builtin_nontemporal_store(lv, (ushort8*)&o_hl[(size_t)node * 256 + 128 + c0]);
    }
  }
}

// ---------------- final: score = clip(z2 @ p3_W + p3_b) ----------------

__global__ void __launch_bounds__(256)
predictor_final(const float* __restrict__ z2, const float* __restrict__ w3,
                const float* __restrict__ b3, float* __restrict__ out, int n) {
  int node = (blockIdx.x << 2) + (threadIdx.x >> 6);
  int lane = threadIdx.x & 63;
  if (node >= n) return;
  float v = z2[(size_t)node * 64 + lane] * w3[lane];
#pragma unroll
  for (int off = 32; off > 0; off >>= 1) v += __shfl_xor(v, off);
  if (lane == 0) {
    float s = v + b3[0];
    s = fminf(fmaxf(s, -15.f), 15.f);
    out[node] = s;
  }
}

// ---------------- launch ----------------

extern "C" void kernel_launch(void* const* d_in, const int* in_sizes, int n_in,
                              void* d_out, int out_size, void* d_ws, size_t ws_size,
                              hipStream_t stream) {
  const float* x     = (const float*)d_in[0];
  const int*   ei    = (const int*)d_in[1];
  const float* emb_W = (const float*)d_in[3];
  const float* emb_b = (const float*)d_in[4];
  const float* Wl    = (const float*)d_in[5];
  const float* bl    = (const float*)d_in[6];
  const float* Wr    = (const float*)d_in[7];
  const float* br    = (const float*)d_in[8];
  const float* att   = (const float*)d_in[9];
  const float* cbias = (const float*)d_in[10];
  const float* p1W   = (const float*)d_in[11];
  const float* p1b   = (const float*)d_in[12];
  const float* p2W   = (const float*)d_in[13];
  const float* p2b   = (const float*)d_in[14];
  const float* p3W   = (const float*)d_in[15];
  const float* p3b   = (const float*)d_in[16];
  float* out = (float*)d_out;

  char* ws = (char*)d_ws;
  size_t o = 0;
  float* h0 = (float*)(ws + o); o += (size_t)NN * 128 * 4;
  float* h1 = (float*)(ws + o); o += (size_t)NN * 128 * 4;
  unsigned short* h_hl = (unsigned short*)(ws + o); o += (size_t)NN * 256 * 2;
  unsigned short* xl_bf = (unsigned short*)(ws + o); o += (size_t)NN * 512 * 2;
  unsigned short* xr_bf = (unsigned short*)(ws + o); o += (size_t)NN * 512 * 2;
  unsigned short* BT = (unsigned short*)(ws + o); o += (size_t)LAYERS * 1024 * 256 * 2;
  unsigned short* BT1 = (unsigned short*)(ws + o); o += (size_t)128 * 256 * 2;
  unsigned short* BT2 = (unsigned short*)(ws + o); o += (size_t)64 * 256 * 2;
  int* indptr = (int*)(ws + o); o += (((size_t)(NN + 1) * 4) + 255) / 256 * 256;
  int* counts = (int*)(ws + o); o += (((size_t)NN * 4) + 255) / 256 * 256;
  int* bsum = (int*)(ws + o); o += 256;
  int* boff = (int*)(ws + o); o += 256;
  int* srcs   = (int*)(ws + o); o += (size_t)NE * 4;

  const int* esrc = ei;
  const int* edst = ei + NE;
  int nb = (NN + 1023) / 1024;

  // CSR build (parallel 3-kernel scan)
  hipMemsetAsync(counts, 0, (size_t)NN * 4, stream);
  hist_kernel<<<(NE + 255) / 256, 256, 0, stream>>>(edst, counts, NE);
  scan1_kernel<<<nb, 1024, 0, stream>>>(counts, indptr, bsum, NN);
  scan2_kernel<<<1, 64, 0, stream>>>(bsum, boff, nb, indptr, NN);
  scan3_kernel<<<nb, 1024, 0, stream>>>(indptr, boff, NN);
  hipMemsetAsync(counts, 0, (size_t)NN * 4, stream);
  scatter_kernel<<<(NE + 255) / 256, 256, 0, stream>>>(esrc, edst, indptr, counts, srcs, NE);

  // weight prep
  prep_w<<<(LAYERS * 1024 * 128) / 256, 256, 0, stream>>>(Wl, Wr, BT);
  prep_p<<<96, 256, 0, stream>>>(p1W, p2W, BT1, BT2);

  // embedding (fp32) + hi/lo split fused
  gemm_bias<1, 1><<<dim3(2, (NN + 63) / 64), 256, 0, stream>>>(
      x, emb_W, emb_b, h0, h_hl, NN, 64, 128);

  float* hc = h0;
  float* hn = h1;
  for (int l = 0; l < LAYERS; ++l) {
    mfma_gemm_pers<<<512, 256, 0, stream>>>(
        h_hl, BT + (size_t)l * 1024 * 256,
        bl + (size_t)l * 512, br + (size_t)l * 512, xl_bf, xr_bf, NN);
    gat_aggregate<<<(NN + 3) / 4, 256, 0, stream>>>(
        xl_bf, xr_bf, indptr, srcs, att + (size_t)l * 512, cbias + (size_t)l * 128,
        hc, hn, h_hl, (l < LAYERS - 1) ? 1 : 0);
    float* t = hc; hc = hn; hn = t;
  }

  // predictor: p1/p2 via MFMA, p3 fp32
  unsigned short* z1_hl = xl_bf;
  float* z2f = (float*)xr_bf;
  mfma_gemm_small<128, 1><<<512, 256, 0, stream>>>(h_hl, BT1, p1b, z1_hl, (float*)0, NN);
  mfma_gemm_small<64, 0><<<512, 256, 0, stream>>>(z1_hl, BT2, p2b, (unsigned short*)0, z2f, NN);
  predictor_final<<<(NN + 3) / 4, 256, 0, stream>>>(z2f, p3W, p3b, out, NN);
}